// Round 2
// baseline (438.124 us; speedup 1.0000x reference)
//
#include <hip/hip_runtime.h>

#define N_NODES 50000
#define N_EDGES 800000
#define N_PADROWS 50048   // 782 * 64
#define NB 782            // dst buckets of 64 nodes each

typedef unsigned int uint;
typedef unsigned short ushort;

typedef __attribute__((ext_vector_type(8))) short short8;
typedef __attribute__((ext_vector_type(4))) float floatx4;

__device__ __forceinline__ ushort f2bf(float f) {
    uint u = __builtin_bit_cast(uint, f);
    u += 0x7fffu + ((u >> 16) & 1u);      // round-to-nearest-even
    return (ushort)(u >> 16);
}
__device__ __forceinline__ float bf2f(ushort h) {
    uint u = ((uint)h) << 16;
    return __builtin_bit_cast(float, u);
}
__device__ __forceinline__ float bflo(uint w) { return __builtin_bit_cast(float, w << 16); }
__device__ __forceinline__ float bfhi(uint w) { return __builtin_bit_cast(float, w & 0xffff0000u); }
__device__ __forceinline__ uint pack2(float a, float b) {
    return (uint)f2bf(a) | ((uint)f2bf(b) << 16);
}

// ---------------- fused init: conv (x->bf16) + zero counts + weight prep ----------------
// block ranges: [0,1563) conv, [1563,1759) zero, [1759,1919) prep
#define CONV_BLOCKS 1563
#define ZERO_BLOCKS 196
#define PREP_BLOCKS 160
#define INIT_BLOCKS (CONV_BLOCKS + ZERO_BLOCKS + PREP_BLOCKS)

__global__ __launch_bounds__(256) void init_k(const float* __restrict__ x,
                                              ushort* __restrict__ hb,
                                              int* __restrict__ counts,
                                              const float* __restrict__ basis,
                                              const float* __restrict__ root,
                                              ushort* __restrict__ Bsw) {
    int b = blockIdx.x;
    if (b < CONV_BLOCKS) {
        // x fp32 -> dense bf16 [N][64], 8 floats per thread
        int i = b * 256 + threadIdx.x;
        if (i >= N_NODES * 8) return;
        const float4* p = (const float4*)(x + (size_t)i * 8);
        float4 a = p[0], c = p[1];
        uint4 o;
        o.x = pack2(a.x, a.y); o.y = pack2(a.z, a.w);
        o.z = pack2(c.x, c.y); o.w = pack2(c.z, c.w);
        *(uint4*)(hb + (size_t)i * 8) = o;
    } else if (b < CONV_BLOCKS + ZERO_BLOCKS) {
        int i = (b - CONV_BLOCKS) * 256 + threadIdx.x;
        if (i < N_NODES) counts[i] = 0;
    } else {
        // Bsw[l][kb][ct][q][n][j] = W_l[kb*32+q*8+j][ct*16+n], W_l = [basis_l ; root_l]
        int idx = (b - (CONV_BLOCKS + ZERO_BLOCKS)) * 256 + threadIdx.x;
        if (idx >= 2 * 20480) return;
        int l = idx / 20480;
        int r = idx % 20480;
        int kb = r >> 11, ct = (r >> 9) & 3, q = (r >> 7) & 3, n = (r >> 3) & 15, j = r & 7;
        int k = kb * 32 + q * 8 + j;
        int c = ct * 16 + n;
        float v = (k < 256) ? basis[(size_t)l * 16384 + k * 64 + c]
                            : root[(size_t)l * 4096 + (k - 256) * 64 + c];
        Bsw[idx] = f2bf(v);
    }
}

// ---------------- CSR build ----------------

__global__ __launch_bounds__(256) void hist_k(const int* __restrict__ ei, int* __restrict__ counts) {
    int e = blockIdx.x * 256 + threadIdx.x;
    if (e < N_EDGES) atomicAdd(&counts[ei[N_EDGES + e]], 1);
}

__global__ __launch_bounds__(1024) void scan1_k(const int* __restrict__ counts,
                                                int* __restrict__ start,
                                                int* __restrict__ bsums) {
    __shared__ int s[1024];
    int i = blockIdx.x * 1024 + threadIdx.x;
    int x = (i < N_NODES) ? counts[i] : 0;
    s[threadIdx.x] = x;
    __syncthreads();
    for (int off = 1; off < 1024; off <<= 1) {
        int v = (threadIdx.x >= off) ? s[threadIdx.x - off] : 0;
        __syncthreads();
        s[threadIdx.x] += v;
        __syncthreads();
    }
    if (i < N_NODES) start[i] = s[threadIdx.x] - x;
    if (threadIdx.x == 1023) bsums[blockIdx.x] = s[1023];
}

// wave-parallel exclusive scan over block sums (nblocks <= 64, one wave)
__global__ void scan2_k(int* __restrict__ bsums, int nblocks) {
    int lane = threadIdx.x;           // launched with 64 threads = one wave
    int v = (lane < nblocks) ? bsums[lane] : 0;
    int x = v;
    #pragma unroll
    for (int off = 1; off < 64; off <<= 1) {
        int t = __shfl_up(x, off, 64);
        if (lane >= off) x += t;
    }
    if (lane < nblocks) bsums[lane] = x - v;   // exclusive
}

__global__ __launch_bounds__(256) void scan3_k(int* __restrict__ start,
                                               int* __restrict__ bcur,
                                               const int* __restrict__ bsums) {
    int i = blockIdx.x * 256 + threadIdx.x;
    if (i < N_NODES) {
        int v = start[i] + bsums[i >> 10];
        start[i] = v;
        if ((i & 63) == 0) bcur[i >> 6] = v;   // bucket frontier cursor = CSR start of bucket
    }
}

// ---------------- binned two-pass scatter ----------------
// pass 1: per edge compute both layers' c = ea @ att; append record pair at the
// dst-bucket frontier (782 hot cursors -> line-dense writes).
// srec[2*pos] = {src, c0lo, c0hi, dst}, srec[2*pos+1] = {src, c1lo, c1hi, 0}
__global__ __launch_bounds__(256) void scatter1_k(const int* __restrict__ ei,
                                                  const float* __restrict__ ea,
                                                  const float* __restrict__ att,   // [2,8,4]
                                                  int* __restrict__ bcur,
                                                  uint4* __restrict__ srec) {
    int e = blockIdx.x * 256 + threadIdx.x;
    if (e >= N_EDGES) return;
    int src = ei[e];
    int dst = ei[N_EDGES + e];

    const float4* eav = (const float4*)(ea + (size_t)e * 8);
    float4 a0 = eav[0], a1 = eav[1];
    float ev[8] = {a0.x, a0.y, a0.z, a0.w, a1.x, a1.y, a1.z, a1.w};

    float4 c0 = make_float4(0.f, 0.f, 0.f, 0.f);
    float4 c1 = make_float4(0.f, 0.f, 0.f, 0.f);
    const float4* att0 = (const float4*)att;
    const float4* att1 = (const float4*)(att + 32);
    #pragma unroll
    for (int r = 0; r < 8; ++r) {
        float4 w0 = att0[r];
        float4 w1 = att1[r];
        c0.x = fmaf(ev[r], w0.x, c0.x); c0.y = fmaf(ev[r], w0.y, c0.y);
        c0.z = fmaf(ev[r], w0.z, c0.z); c0.w = fmaf(ev[r], w0.w, c0.w);
        c1.x = fmaf(ev[r], w1.x, c1.x); c1.y = fmaf(ev[r], w1.y, c1.y);
        c1.z = fmaf(ev[r], w1.z, c1.z); c1.w = fmaf(ev[r], w1.w, c1.w);
    }
    int pos = atomicAdd(&bcur[dst >> 6], 1);
    srec[2 * (size_t)pos]     = make_uint4((uint)src, pack2(c0.x, c0.y), pack2(c0.z, c0.w), (uint)dst);
    srec[2 * (size_t)pos + 1] = make_uint4((uint)src, pack2(c1.x, c1.y), pack2(c1.z, c1.w), 0u);
}

// pass 2: one workgroup per bucket. Reads its ~32KB staging window sequentially,
// assigns exact per-node slots via LDS cursors (zero global atomics), writes the
// final CSR-ordered records into the same-sized, L2-warm output window.
__global__ __launch_bounds__(256) void scatter2_k(const int* __restrict__ start,
                                                  const uint4* __restrict__ srec,
                                                  uint4* __restrict__ rec) {
    __shared__ int lcur[64];
    int b = blockIdx.x;
    int n0 = b << 6;
    if (threadIdx.x < 64) {
        int n = n0 + threadIdx.x;
        lcur[threadIdx.x] = (n < N_NODES) ? start[n] : N_EDGES;
    }
    int lo = start[n0];
    int hi = (b == NB - 1) ? N_EDGES : start[n0 + 64];
    __syncthreads();
    for (int i = lo + threadIdx.x; i < hi; i += 256) {
        uint4 r0 = srec[2 * (size_t)i];
        uint4 r1 = srec[2 * (size_t)i + 1];
        int slot = atomicAdd(&lcur[(int)r0.w - n0], 1);
        rec[2 * (size_t)slot]     = r0;
        rec[2 * (size_t)slot + 1] = r1;
    }
}

// ---------------- per-layer kernels ----------------

// one wave per dst node; lane = channel. recs = rec (+1 for layer 1), stride 2 uint4/edge.
// gathers from dense hb [N][64] bf16 (6.4MB, L2-resident); writes y row [256] bf16.
__global__ __launch_bounds__(256) void agg_k(const int* __restrict__ start,
                                             const int* __restrict__ counts,
                                             const uint4* __restrict__ recs,
                                             const ushort* __restrict__ hb,
                                             ushort* __restrict__ y16) {
    int node = blockIdx.x * 4 + (threadIdx.x >> 6);
    int lane = threadIdx.x & 63;
    if (node >= N_NODES) return;
    int s = start[node];
    int cnt = counts[node];

    float y0 = 0.f, y1 = 0.f, y2 = 0.f, y3 = 0.f;
    int j = 0;
    for (; j + 7 < cnt; j += 8) {
        uint4 r[8];
        #pragma unroll
        for (int i = 0; i < 8; ++i) r[i] = recs[2 * (size_t)(s + j + i)];
        float hv[8];
        #pragma unroll
        for (int i = 0; i < 8; ++i) hv[i] = bf2f(hb[(size_t)r[i].x * 64 + lane]);
        #pragma unroll
        for (int i = 0; i < 8; ++i) {
            y0 = fmaf(bflo(r[i].y), hv[i], y0);
            y1 = fmaf(bfhi(r[i].y), hv[i], y1);
            y2 = fmaf(bflo(r[i].z), hv[i], y2);
            y3 = fmaf(bfhi(r[i].z), hv[i], y3);
        }
    }
    for (; j + 1 < cnt; j += 2) {
        uint4 ra = recs[2 * (size_t)(s + j)];
        uint4 rb = recs[2 * (size_t)(s + j + 1)];
        float ha = bf2f(hb[(size_t)ra.x * 64 + lane]);
        float hbv = bf2f(hb[(size_t)rb.x * 64 + lane]);
        y0 = fmaf(bflo(ra.y), ha, y0); y1 = fmaf(bfhi(ra.y), ha, y1);
        y2 = fmaf(bflo(ra.z), ha, y2); y3 = fmaf(bfhi(ra.z), ha, y3);
        y0 = fmaf(bflo(rb.y), hbv, y0); y1 = fmaf(bfhi(rb.y), hbv, y1);
        y2 = fmaf(bflo(rb.z), hbv, y2); y3 = fmaf(bfhi(rb.z), hbv, y3);
    }
    if (j < cnt) {
        uint4 r = recs[2 * (size_t)(s + j)];
        float hv = bf2f(hb[(size_t)r.x * 64 + lane]);
        y0 = fmaf(bflo(r.y), hv, y0); y1 = fmaf(bfhi(r.y), hv, y1);
        y2 = fmaf(bflo(r.z), hv, y2); y3 = fmaf(bfhi(r.z), hv, y3);
    }
    ushort* yr = y16 + (size_t)node * 256;
    yr[lane]       = f2bf(y0);
    yr[64 + lane]  = f2bf(y1);
    yr[128 + lane] = f2bf(y2);
    yr[192 + lane] = f2bf(y3);
}

// MFMA GEMM: out[n][c] = sum_{k<320} [y16|hb][n][k] * W[k][c] + bias[c]
// One wave computes 16 rows x 64 cols. A: kb 0..7 from y16 [N][256], kb 8..9 from hb [N][64].
__global__ __launch_bounds__(256) void gemm_k(const ushort* __restrict__ y16,   // [N_PADROWS][256] bf16
                                              const ushort* __restrict__ hb,    // [N_PADROWS][64] bf16
                                              const ushort* __restrict__ Bsw,   // [2560][8] bf16 fragment order
                                              const float* __restrict__ bias,   // [64]
                                              float* __restrict__ outf,         // fp32 out or null
                                              ushort* __restrict__ outh,        // next hb (bf16) or null
                                              int relu) {
    __shared__ uint4 bs[2560];   // 40 KB
    const int tid = threadIdx.x;
    for (int i = tid; i < 2560; i += 256) bs[i] = ((const uint4*)Bsw)[i];

    const int lane = tid & 63;
    const int wid = tid >> 6;
    const int nlo = lane & 15;
    const int quad = lane >> 4;
    const int m0 = blockIdx.x * 64 + wid * 16;

    floatx4 acc[4];
    #pragma unroll
    for (int ct = 0; ct < 4; ++ct) acc[ct] = (floatx4){0.f, 0.f, 0.f, 0.f};

    const ushort* yrow = y16 + (size_t)(m0 + nlo) * 256 + quad * 8;
    const ushort* hrow = hb  + (size_t)(m0 + nlo) * 64  + quad * 8;
    __syncthreads();

    #pragma unroll
    for (int kb = 0; kb < 10; ++kb) {
        uint4 av = (kb < 8) ? *(const uint4*)(yrow + kb * 32)
                            : *(const uint4*)(hrow + (kb - 8) * 32);
        short8 a = __builtin_bit_cast(short8, av);
        #pragma unroll
        for (int ct = 0; ct < 4; ++ct) {
            short8 b = __builtin_bit_cast(short8, bs[(kb * 4 + ct) * 64 + lane]);
            acc[ct] = __builtin_amdgcn_mfma_f32_16x16x32_bf16(a, b, acc[ct], 0, 0, 0);
        }
    }

    // C/D layout: col = ct*16 + (lane&15), row = quad*4 + reg
    #pragma unroll
    for (int ct = 0; ct < 4; ++ct) {
        int col = ct * 16 + nlo;
        float bv = bias[col];
        #pragma unroll
        for (int r = 0; r < 4; ++r) {
            int row = m0 + quad * 4 + r;
            if (row < N_NODES) {
                float v = acc[ct][r] + bv;
                if (relu) v = fmaxf(v, 0.f);
                if (outf) outf[(size_t)row * 64 + col] = v;
                if (outh) outh[(size_t)row * 64 + col] = f2bf(v);
            }
        }
    }
}

// ---------------- launch ----------------

extern "C" void kernel_launch(void* const* d_in, const int* in_sizes, int n_in,
                              void* d_out, int out_size, void* d_ws, size_t ws_size,
                              hipStream_t stream) {
    const float* x     = (const float*)d_in[0];
    const int*   ei    = (const int*)d_in[1];
    const float* ea    = (const float*)d_in[2];
    const float* basis = (const float*)d_in[3];  // [2,4,64,64]
    const float* att   = (const float*)d_in[4];  // [2,8,4]
    const float* root  = (const float*)d_in[5];  // [2,64,64]
    const float* bias  = (const float*)d_in[6];  // [2,64]
    float* out = (float*)d_out;

    char* p = (char*)d_ws;
    uint4*  rec    = (uint4*)p;   p += (size_t)N_EDGES * 32;          // 25.6 MB
    ushort* y16    = (ushort*)p;  p += (size_t)N_PADROWS * 256 * 2;   // 25.6 MB (also staging srec)
    ushort* hb0    = (ushort*)p;  p += (size_t)N_PADROWS * 64 * 2;    //  6.4 MB (x bf16)
    ushort* hb1    = (ushort*)p;  p += (size_t)N_PADROWS * 64 * 2;    //  6.4 MB (h1 bf16)
    ushort* Bsw    = (ushort*)p;  p += (size_t)2 * 20480 * 2;         //  80 KB
    int*    counts = (int*)p;     p += (size_t)N_NODES * 4;
    int*    start  = (int*)p;     p += (size_t)N_NODES * 4;
    int*    bcur   = (int*)p;     p += (size_t)1024 * 4;
    int*    bsums  = (int*)p;     p += 64 * 4;

    uint4* srec = (uint4*)y16;   // staging records: y16 is dead until agg L0 writes it

    const int scan_blocks = (N_NODES + 1023) / 1024;  // 49

    init_k<<<INIT_BLOCKS, 256, 0, stream>>>(x, hb0, counts, basis, root, Bsw);
    hist_k<<<(N_EDGES + 255) / 256, 256, 0, stream>>>(ei, counts);
    scan1_k<<<scan_blocks, 1024, 0, stream>>>(counts, start, bsums);
    scan2_k<<<1, 64, 0, stream>>>(bsums, scan_blocks);
    scan3_k<<<(N_NODES + 255) / 256, 256, 0, stream>>>(start, bcur, bsums);
    scatter1_k<<<(N_EDGES + 255) / 256, 256, 0, stream>>>(ei, ea, att, bcur, srec);
    scatter2_k<<<NB, 256, 0, stream>>>(start, srec, rec);

    dim3 agg_grid((N_NODES + 3) / 4);
    dim3 gemm_grid(N_PADROWS / 64);   // 782

    // ---- layer 0: h = x (hb0) -> h1 bf16 (hb1) ---- (agg overwrites y16/srec after scatter2)
    agg_k<<<agg_grid, 256, 0, stream>>>(start, counts, rec, hb0, y16);
    gemm_k<<<gemm_grid, 256, 0, stream>>>(y16, hb0, Bsw, bias, (float*)0, hb1, 1);

    // ---- layer 1: h = h1 (hb1) -> out fp32 ----
    agg_k<<<agg_grid, 256, 0, stream>>>(start, counts, rec + 1, hb1, y16);
    gemm_k<<<gemm_grid, 256, 0, stream>>>(y16, hb1, Bsw + 20480, bias + 64, out, (ushort*)0, 0);
}

// Round 3
// 296.013 us; speedup vs baseline: 1.4801x; 1.4801x over previous
//
#include <hip/hip_runtime.h>

#define N_NODES 50000
#define N_EDGES 800000
#define N_PADROWS 50048   // 782 * 64
#define NB 782            // dst buckets of 64 nodes each

typedef unsigned int uint;
typedef unsigned short ushort;

typedef __attribute__((ext_vector_type(8))) short short8;
typedef __attribute__((ext_vector_type(4))) float floatx4;

__device__ __forceinline__ ushort f2bf(float f) {
    uint u = __builtin_bit_cast(uint, f);
    u += 0x7fffu + ((u >> 16) & 1u);      // round-to-nearest-even
    return (ushort)(u >> 16);
}
__device__ __forceinline__ float bf2f(ushort h) {
    uint u = ((uint)h) << 16;
    return __builtin_bit_cast(float, u);
}
__device__ __forceinline__ float bflo(uint w) { return __builtin_bit_cast(float, w << 16); }
__device__ __forceinline__ float bfhi(uint w) { return __builtin_bit_cast(float, w & 0xffff0000u); }
__device__ __forceinline__ uint pack2(float a, float b) {
    return (uint)f2bf(a) | ((uint)f2bf(b) << 16);
}

// ---------------- fused init: conv (x->bf16) + zero counts + weight prep ----------------
// block ranges: [0,1563) conv, [1563,1759) zero, [1759,1919) prep
#define CONV_BLOCKS 1563
#define ZERO_BLOCKS 196
#define PREP_BLOCKS 160
#define INIT_BLOCKS (CONV_BLOCKS + ZERO_BLOCKS + PREP_BLOCKS)

__global__ __launch_bounds__(256) void init_k(const float* __restrict__ x,
                                              ushort* __restrict__ hb,
                                              int* __restrict__ counts,
                                              const float* __restrict__ basis,
                                              const float* __restrict__ root,
                                              ushort* __restrict__ Bsw) {
    int b = blockIdx.x;
    if (b < CONV_BLOCKS) {
        // x fp32 -> dense bf16 [N][64], 8 floats per thread
        int i = b * 256 + threadIdx.x;
        if (i >= N_NODES * 8) return;
        const float4* p = (const float4*)(x + (size_t)i * 8);
        float4 a = p[0], c = p[1];
        uint4 o;
        o.x = pack2(a.x, a.y); o.y = pack2(a.z, a.w);
        o.z = pack2(c.x, c.y); o.w = pack2(c.z, c.w);
        *(uint4*)(hb + (size_t)i * 8) = o;
    } else if (b < CONV_BLOCKS + ZERO_BLOCKS) {
        int i = (b - CONV_BLOCKS) * 256 + threadIdx.x;
        if (i < N_NODES) counts[i] = 0;
    } else {
        // Bsw[l][kb][ct][q][n][j] = W_l[kb*32+q*8+j][ct*16+n], W_l = [basis_l ; root_l]
        int idx = (b - (CONV_BLOCKS + ZERO_BLOCKS)) * 256 + threadIdx.x;
        if (idx >= 2 * 20480) return;
        int l = idx / 20480;
        int r = idx % 20480;
        int kb = r >> 11, ct = (r >> 9) & 3, q = (r >> 7) & 3, n = (r >> 3) & 15, j = r & 7;
        int k = kb * 32 + q * 8 + j;
        int c = ct * 16 + n;
        float v = (k < 256) ? basis[(size_t)l * 16384 + k * 64 + c]
                            : root[(size_t)l * 4096 + (k - 256) * 64 + c];
        Bsw[idx] = f2bf(v);
    }
}

// ---------------- CSR build ----------------

__global__ __launch_bounds__(256) void hist_k(const int* __restrict__ ei, int* __restrict__ counts) {
    int e = blockIdx.x * 256 + threadIdx.x;
    if (e < N_EDGES) atomicAdd(&counts[ei[N_EDGES + e]], 1);
}

__global__ __launch_bounds__(1024) void scan1_k(const int* __restrict__ counts,
                                                int* __restrict__ start,
                                                int* __restrict__ bsums) {
    __shared__ int s[1024];
    int i = blockIdx.x * 1024 + threadIdx.x;
    int x = (i < N_NODES) ? counts[i] : 0;
    s[threadIdx.x] = x;
    __syncthreads();
    for (int off = 1; off < 1024; off <<= 1) {
        int v = (threadIdx.x >= off) ? s[threadIdx.x - off] : 0;
        __syncthreads();
        s[threadIdx.x] += v;
        __syncthreads();
    }
    if (i < N_NODES) start[i] = s[threadIdx.x] - x;
    if (threadIdx.x == 1023) bsums[blockIdx.x] = s[1023];
}

// wave-parallel exclusive scan over block sums (nblocks <= 64, one wave)
__global__ void scan2_k(int* __restrict__ bsums, int nblocks) {
    int lane = threadIdx.x;           // launched with 64 threads = one wave
    int v = (lane < nblocks) ? bsums[lane] : 0;
    int x = v;
    #pragma unroll
    for (int off = 1; off < 64; off <<= 1) {
        int t = __shfl_up(x, off, 64);
        if (lane >= off) x += t;
    }
    if (lane < nblocks) bsums[lane] = x - v;   // exclusive
}

// bucket cursors padded to ONE PER 64B LINE: bcur[b*16].
// (round-2 regression root cause: 16 cursors/line -> 800K atomics serialized on ~49 lines)
__global__ __launch_bounds__(256) void scan3_k(int* __restrict__ start,
                                               int* __restrict__ bcur,
                                               const int* __restrict__ bsums) {
    int i = blockIdx.x * 256 + threadIdx.x;
    if (i < N_NODES) {
        int v = start[i] + bsums[i >> 10];
        start[i] = v;
        if ((i & 63) == 0) bcur[(i >> 6) * 16] = v;   // padded bucket frontier cursor
    }
}

// ---------------- binned two-pass scatter ----------------
// pass 1: per edge compute both layers' c = ea @ att; append record pair at the
// dst-bucket frontier (782 line-padded cursors -> line-dense writes).
// srec[2*pos] = {src, c0lo, c0hi, dst}, srec[2*pos+1] = {src, c1lo, c1hi, 0}
__global__ __launch_bounds__(256) void scatter1_k(const int* __restrict__ ei,
                                                  const float* __restrict__ ea,
                                                  const float* __restrict__ att,   // [2,8,4]
                                                  int* __restrict__ bcur,
                                                  uint4* __restrict__ srec) {
    int e = blockIdx.x * 256 + threadIdx.x;
    if (e >= N_EDGES) return;
    int src = ei[e];
    int dst = ei[N_EDGES + e];

    const float4* eav = (const float4*)(ea + (size_t)e * 8);
    float4 a0 = eav[0], a1 = eav[1];
    float ev[8] = {a0.x, a0.y, a0.z, a0.w, a1.x, a1.y, a1.z, a1.w};

    float4 c0 = make_float4(0.f, 0.f, 0.f, 0.f);
    float4 c1 = make_float4(0.f, 0.f, 0.f, 0.f);
    const float4* att0 = (const float4*)att;
    const float4* att1 = (const float4*)(att + 32);
    #pragma unroll
    for (int r = 0; r < 8; ++r) {
        float4 w0 = att0[r];
        float4 w1 = att1[r];
        c0.x = fmaf(ev[r], w0.x, c0.x); c0.y = fmaf(ev[r], w0.y, c0.y);
        c0.z = fmaf(ev[r], w0.z, c0.z); c0.w = fmaf(ev[r], w0.w, c0.w);
        c1.x = fmaf(ev[r], w1.x, c1.x); c1.y = fmaf(ev[r], w1.y, c1.y);
        c1.z = fmaf(ev[r], w1.z, c1.z); c1.w = fmaf(ev[r], w1.w, c1.w);
    }
    int pos = atomicAdd(&bcur[(dst >> 6) * 16], 1);
    srec[2 * (size_t)pos]     = make_uint4((uint)src, pack2(c0.x, c0.y), pack2(c0.z, c0.w), (uint)dst);
    srec[2 * (size_t)pos + 1] = make_uint4((uint)src, pack2(c1.x, c1.y), pack2(c1.z, c1.w), 0u);
}

// pass 2: one workgroup per bucket. Reads its ~32KB staging window sequentially,
// assigns exact per-node slots via LDS cursors (zero global atomics), writes the
// final CSR-ordered records into the same-sized, L2-warm output window.
__global__ __launch_bounds__(256) void scatter2_k(const int* __restrict__ start,
                                                  const uint4* __restrict__ srec,
                                                  uint4* __restrict__ rec) {
    __shared__ int lcur[64];
    int b = blockIdx.x;
    int n0 = b << 6;
    if (threadIdx.x < 64) {
        int n = n0 + threadIdx.x;
        lcur[threadIdx.x] = (n < N_NODES) ? start[n] : N_EDGES;
    }
    int lo = start[n0];
    int hi = (b == NB - 1) ? N_EDGES : start[n0 + 64];
    __syncthreads();
    for (int i = lo + threadIdx.x; i < hi; i += 256) {
        uint4 r0 = srec[2 * (size_t)i];
        uint4 r1 = srec[2 * (size_t)i + 1];
        int slot = atomicAdd(&lcur[(int)r0.w - n0], 1);
        rec[2 * (size_t)slot]     = r0;
        rec[2 * (size_t)slot + 1] = r1;
    }
}

// ---------------- per-layer kernels ----------------

// one wave per dst node; lane = channel. recs = rec (+1 for layer 1), stride 2 uint4/edge.
// gathers from dense hb [N][64] bf16 (6.4MB, L2-resident); writes y row [256] bf16.
__global__ __launch_bounds__(256) void agg_k(const int* __restrict__ start,
                                             const int* __restrict__ counts,
                                             const uint4* __restrict__ recs,
                                             const ushort* __restrict__ hb,
                                             ushort* __restrict__ y16) {
    int node = blockIdx.x * 4 + (threadIdx.x >> 6);
    int lane = threadIdx.x & 63;
    if (node >= N_NODES) return;
    int s = start[node];
    int cnt = counts[node];

    float y0 = 0.f, y1 = 0.f, y2 = 0.f, y3 = 0.f;
    int j = 0;
    for (; j + 7 < cnt; j += 8) {
        uint4 r[8];
        #pragma unroll
        for (int i = 0; i < 8; ++i) r[i] = recs[2 * (size_t)(s + j + i)];
        float hv[8];
        #pragma unroll
        for (int i = 0; i < 8; ++i) hv[i] = bf2f(hb[(size_t)r[i].x * 64 + lane]);
        #pragma unroll
        for (int i = 0; i < 8; ++i) {
            y0 = fmaf(bflo(r[i].y), hv[i], y0);
            y1 = fmaf(bfhi(r[i].y), hv[i], y1);
            y2 = fmaf(bflo(r[i].z), hv[i], y2);
            y3 = fmaf(bfhi(r[i].z), hv[i], y3);
        }
    }
    for (; j + 1 < cnt; j += 2) {
        uint4 ra = recs[2 * (size_t)(s + j)];
        uint4 rb = recs[2 * (size_t)(s + j + 1)];
        float ha = bf2f(hb[(size_t)ra.x * 64 + lane]);
        float hbv = bf2f(hb[(size_t)rb.x * 64 + lane]);
        y0 = fmaf(bflo(ra.y), ha, y0); y1 = fmaf(bfhi(ra.y), ha, y1);
        y2 = fmaf(bflo(ra.z), ha, y2); y3 = fmaf(bfhi(ra.z), ha, y3);
        y0 = fmaf(bflo(rb.y), hbv, y0); y1 = fmaf(bfhi(rb.y), hbv, y1);
        y2 = fmaf(bflo(rb.z), hbv, y2); y3 = fmaf(bfhi(rb.z), hbv, y3);
    }
    if (j < cnt) {
        uint4 r = recs[2 * (size_t)(s + j)];
        float hv = bf2f(hb[(size_t)r.x * 64 + lane]);
        y0 = fmaf(bflo(r.y), hv, y0); y1 = fmaf(bfhi(r.y), hv, y1);
        y2 = fmaf(bflo(r.z), hv, y2); y3 = fmaf(bfhi(r.z), hv, y3);
    }
    ushort* yr = y16 + (size_t)node * 256;
    yr[lane]       = f2bf(y0);
    yr[64 + lane]  = f2bf(y1);
    yr[128 + lane] = f2bf(y2);
    yr[192 + lane] = f2bf(y3);
}

// MFMA GEMM: out[n][c] = sum_{k<320} [y16|hb][n][k] * W[k][c] + bias[c]
// One wave computes 16 rows x 64 cols. A: kb 0..7 from y16 [N][256], kb 8..9 from hb [N][64].
__global__ __launch_bounds__(256) void gemm_k(const ushort* __restrict__ y16,   // [N_PADROWS][256] bf16
                                              const ushort* __restrict__ hb,    // [N_PADROWS][64] bf16
                                              const ushort* __restrict__ Bsw,   // [2560][8] bf16 fragment order
                                              const float* __restrict__ bias,   // [64]
                                              float* __restrict__ outf,         // fp32 out or null
                                              ushort* __restrict__ outh,        // next hb (bf16) or null
                                              int relu) {
    __shared__ uint4 bs[2560];   // 40 KB
    const int tid = threadIdx.x;
    for (int i = tid; i < 2560; i += 256) bs[i] = ((const uint4*)Bsw)[i];

    const int lane = tid & 63;
    const int wid = tid >> 6;
    const int nlo = lane & 15;
    const int quad = lane >> 4;
    const int m0 = blockIdx.x * 64 + wid * 16;

    floatx4 acc[4];
    #pragma unroll
    for (int ct = 0; ct < 4; ++ct) acc[ct] = (floatx4){0.f, 0.f, 0.f, 0.f};

    const ushort* yrow = y16 + (size_t)(m0 + nlo) * 256 + quad * 8;
    const ushort* hrow = hb  + (size_t)(m0 + nlo) * 64  + quad * 8;
    __syncthreads();

    #pragma unroll
    for (int kb = 0; kb < 10; ++kb) {
        uint4 av = (kb < 8) ? *(const uint4*)(yrow + kb * 32)
                            : *(const uint4*)(hrow + (kb - 8) * 32);
        short8 a = __builtin_bit_cast(short8, av);
        #pragma unroll
        for (int ct = 0; ct < 4; ++ct) {
            short8 b = __builtin_bit_cast(short8, bs[(kb * 4 + ct) * 64 + lane]);
            acc[ct] = __builtin_amdgcn_mfma_f32_16x16x32_bf16(a, b, acc[ct], 0, 0, 0);
        }
    }

    // C/D layout: col = ct*16 + (lane&15), row = quad*4 + reg
    #pragma unroll
    for (int ct = 0; ct < 4; ++ct) {
        int col = ct * 16 + nlo;
        float bv = bias[col];
        #pragma unroll
        for (int r = 0; r < 4; ++r) {
            int row = m0 + quad * 4 + r;
            if (row < N_NODES) {
                float v = acc[ct][r] + bv;
                if (relu) v = fmaxf(v, 0.f);
                if (outf) outf[(size_t)row * 64 + col] = v;
                if (outh) outh[(size_t)row * 64 + col] = f2bf(v);
            }
        }
    }
}

// ---------------- launch ----------------

extern "C" void kernel_launch(void* const* d_in, const int* in_sizes, int n_in,
                              void* d_out, int out_size, void* d_ws, size_t ws_size,
                              hipStream_t stream) {
    const float* x     = (const float*)d_in[0];
    const int*   ei    = (const int*)d_in[1];
    const float* ea    = (const float*)d_in[2];
    const float* basis = (const float*)d_in[3];  // [2,4,64,64]
    const float* att   = (const float*)d_in[4];  // [2,8,4]
    const float* root  = (const float*)d_in[5];  // [2,64,64]
    const float* bias  = (const float*)d_in[6];  // [2,64]
    float* out = (float*)d_out;

    char* p = (char*)d_ws;
    uint4*  rec    = (uint4*)p;   p += (size_t)N_EDGES * 32;          // 25.6 MB
    ushort* y16    = (ushort*)p;  p += (size_t)N_PADROWS * 256 * 2;   // 25.6 MB (also staging srec)
    ushort* hb0    = (ushort*)p;  p += (size_t)N_PADROWS * 64 * 2;    //  6.4 MB (x bf16)
    ushort* hb1    = (ushort*)p;  p += (size_t)N_PADROWS * 64 * 2;    //  6.4 MB (h1 bf16)
    ushort* Bsw    = (ushort*)p;  p += (size_t)2 * 20480 * 2;         //  80 KB
    int*    counts = (int*)p;     p += (size_t)N_NODES * 4;
    int*    start  = (int*)p;     p += (size_t)N_NODES * 4;
    int*    bcur   = (int*)p;     p += (size_t)1024 * 16 * 4;         //  64 KB (line-padded cursors)
    int*    bsums  = (int*)p;     p += 64 * 4;

    uint4* srec = (uint4*)y16;   // staging records: y16 is dead until agg L0 writes it

    const int scan_blocks = (N_NODES + 1023) / 1024;  // 49

    init_k<<<INIT_BLOCKS, 256, 0, stream>>>(x, hb0, counts, basis, root, Bsw);
    hist_k<<<(N_EDGES + 255) / 256, 256, 0, stream>>>(ei, counts);
    scan1_k<<<scan_blocks, 1024, 0, stream>>>(counts, start, bsums);
    scan2_k<<<1, 64, 0, stream>>>(bsums, scan_blocks);
    scan3_k<<<(N_NODES + 255) / 256, 256, 0, stream>>>(start, bcur, bsums);
    scatter1_k<<<(N_EDGES + 255) / 256, 256, 0, stream>>>(ei, ea, att, bcur, srec);
    scatter2_k<<<NB, 256, 0, stream>>>(start, srec, rec);

    dim3 agg_grid((N_NODES + 3) / 4);
    dim3 gemm_grid(N_PADROWS / 64);   // 782

    // ---- layer 0: h = x (hb0) -> h1 bf16 (hb1) ---- (agg overwrites y16/srec after scatter2)
    agg_k<<<agg_grid, 256, 0, stream>>>(start, counts, rec, hb0, y16);
    gemm_k<<<gemm_grid, 256, 0, stream>>>(y16, hb0, Bsw, bias, (float*)0, hb1, 1);

    // ---- layer 1: h = h1 (hb1) -> out fp32 ----
    agg_k<<<agg_grid, 256, 0, stream>>>(start, counts, rec + 1, hb1, y16);
    gemm_k<<<gemm_grid, 256, 0, stream>>>(y16, hb1, Bsw + 20480, bias + 64, out, (ushort*)0, 0);
}

// Round 5
// 282.964 us; speedup vs baseline: 1.5483x; 1.0461x over previous
//
#include <hip/hip_runtime.h>

#define N_NODES 50000
#define N_EDGES 800000
#define N_PADROWS 50048   // kept for buffer sizing

typedef unsigned int uint;
typedef unsigned short ushort;

typedef __attribute__((ext_vector_type(8))) short short8;
typedef __attribute__((ext_vector_type(4))) float floatx4;

__device__ __forceinline__ ushort f2bf(float f) {
    uint u = __builtin_bit_cast(uint, f);
    u += 0x7fffu + ((u >> 16) & 1u);      // round-to-nearest-even
    return (ushort)(u >> 16);
}
__device__ __forceinline__ float bf2f(ushort h) {
    uint u = ((uint)h) << 16;
    return __builtin_bit_cast(float, u);
}
__device__ __forceinline__ float bflo(uint w) { return __builtin_bit_cast(float, w << 16); }
__device__ __forceinline__ float bfhi(uint w) { return __builtin_bit_cast(float, w & 0xffff0000u); }
__device__ __forceinline__ uint pack2(float a, float b) {
    return (uint)f2bf(a) | ((uint)f2bf(b) << 16);
}

// ---------------- fused init: conv (x->bf16) + zero counts + weight prep ----------------
// block ranges: [0,1563) conv, [1563,1759) zero, [1759,1919) prep
#define CONV_BLOCKS 1563
#define ZERO_BLOCKS 196
#define PREP_BLOCKS 160
#define INIT_BLOCKS (CONV_BLOCKS + ZERO_BLOCKS + PREP_BLOCKS)

__global__ __launch_bounds__(256) void init_k(const float* __restrict__ x,
                                              ushort* __restrict__ hb,
                                              int* __restrict__ counts,
                                              const float* __restrict__ basis,
                                              const float* __restrict__ root,
                                              ushort* __restrict__ Bsw) {
    int b = blockIdx.x;
    if (b < CONV_BLOCKS) {
        // x fp32 -> dense bf16 [N][64], 8 floats per thread
        int i = b * 256 + threadIdx.x;
        if (i >= N_NODES * 8) return;
        const float4* p = (const float4*)(x + (size_t)i * 8);
        float4 a = p[0], c = p[1];
        uint4 o;
        o.x = pack2(a.x, a.y); o.y = pack2(a.z, a.w);
        o.z = pack2(c.x, c.y); o.w = pack2(c.z, c.w);
        *(uint4*)(hb + (size_t)i * 8) = o;
    } else if (b < CONV_BLOCKS + ZERO_BLOCKS) {
        int i = (b - CONV_BLOCKS) * 256 + threadIdx.x;
        if (i < N_NODES) counts[i] = 0;
    } else {
        // Bsw[l][kb][ct][q][n][j] = W_l[kb*32+q*8+j][ct*16+n], W_l = [basis_l ; root_l]
        int idx = (b - (CONV_BLOCKS + ZERO_BLOCKS)) * 256 + threadIdx.x;
        if (idx >= 2 * 20480) return;
        int l = idx / 20480;
        int r = idx % 20480;
        int kb = r >> 11, ct = (r >> 9) & 3, q = (r >> 7) & 3, n = (r >> 3) & 15, j = r & 7;
        int k = kb * 32 + q * 8 + j;
        int c = ct * 16 + n;
        float v = (k < 256) ? basis[(size_t)l * 16384 + k * 64 + c]
                            : root[(size_t)l * 4096 + (k - 256) * 64 + c];
        Bsw[idx] = f2bf(v);
    }
}

// ---------------- CSR build ----------------

__global__ __launch_bounds__(256) void hist_k(const int* __restrict__ ei, int* __restrict__ counts) {
    int e = blockIdx.x * 256 + threadIdx.x;
    if (e < N_EDGES) atomicAdd(&counts[ei[N_EDGES + e]], 1);
}

__global__ __launch_bounds__(1024) void scan1_k(const int* __restrict__ counts,
                                                int* __restrict__ start,
                                                int* __restrict__ bsums) {
    __shared__ int s[1024];
    int i = blockIdx.x * 1024 + threadIdx.x;
    int x = (i < N_NODES) ? counts[i] : 0;
    s[threadIdx.x] = x;
    __syncthreads();
    for (int off = 1; off < 1024; off <<= 1) {
        int v = (threadIdx.x >= off) ? s[threadIdx.x - off] : 0;
        __syncthreads();
        s[threadIdx.x] += v;
        __syncthreads();
    }
    if (i < N_NODES) start[i] = s[threadIdx.x] - x;
    if (threadIdx.x == 1023) bsums[blockIdx.x] = s[1023];
}

// wave-parallel exclusive scan over block sums (nblocks <= 64, one wave)
__global__ void scan2_k(int* __restrict__ bsums, int nblocks) {
    int lane = threadIdx.x;           // launched with 64 threads = one wave
    int v = (lane < nblocks) ? bsums[lane] : 0;
    int x = v;
    #pragma unroll
    for (int off = 1; off < 64; off <<= 1) {
        int t = __shfl_up(x, off, 64);
        if (lane >= off) x += t;
    }
    if (lane < nblocks) bsums[lane] = x - v;   // exclusive
}

__global__ __launch_bounds__(256) void scan3_k(int* __restrict__ start,
                                               int* __restrict__ cursor,
                                               const int* __restrict__ bsums) {
    int i = blockIdx.x * 256 + threadIdx.x;
    if (i < N_NODES) {
        int v = start[i] + bsums[i >> 10];
        start[i] = v;
        cursor[i] = v;
    }
}

// single-pass scatter (round-1 proven), 2 edges/thread for 2x memory-level parallelism.
// per edge: both layers' c = ea @ att; one 64B-line record pair at the CSR slot.
// rec[2*pos] = {src, c0lo, c0hi, 0}, rec[2*pos+1] = {src, c1lo, c1hi, 0}
__global__ __launch_bounds__(256) void scatter_k(const int* __restrict__ ei,
                                                 const float* __restrict__ ea,
                                                 const float* __restrict__ att,   // [2,8,4]
                                                 int* __restrict__ cursor,
                                                 uint4* __restrict__ rec) {
    int e0 = blockIdx.x * 512 + threadIdx.x;
    const float4* att0 = (const float4*)att;
    const float4* att1 = (const float4*)(att + 32);

    int   src[2], dst[2];
    float4 ca[2], cb[2];
    bool  ok[2];

    // phase 1: issue all independent loads + compute (no cross-edge deps)
    #pragma unroll
    for (int u = 0; u < 2; ++u) {
        int e = e0 + u * 256;
        ok[u] = (e < N_EDGES);
        if (!ok[u]) continue;
        src[u] = ei[e];
        dst[u] = ei[N_EDGES + e];
        const float4* eav = (const float4*)(ea + (size_t)e * 8);
        float4 a0 = eav[0], a1 = eav[1];
        float ev[8] = {a0.x, a0.y, a0.z, a0.w, a1.x, a1.y, a1.z, a1.w};
        float4 c0 = make_float4(0.f, 0.f, 0.f, 0.f);
        float4 c1 = make_float4(0.f, 0.f, 0.f, 0.f);
        #pragma unroll
        for (int r = 0; r < 8; ++r) {
            float4 w0 = att0[r];
            float4 w1 = att1[r];
            c0.x = fmaf(ev[r], w0.x, c0.x); c0.y = fmaf(ev[r], w0.y, c0.y);
            c0.z = fmaf(ev[r], w0.z, c0.z); c0.w = fmaf(ev[r], w0.w, c0.w);
            c1.x = fmaf(ev[r], w1.x, c1.x); c1.y = fmaf(ev[r], w1.y, c1.y);
            c1.z = fmaf(ev[r], w1.z, c1.z); c1.w = fmaf(ev[r], w1.w, c1.w);
        }
        ca[u] = c0; cb[u] = c1;
    }

    // phase 2: independent atomics
    int pos[2];
    #pragma unroll
    for (int u = 0; u < 2; ++u)
        if (ok[u]) pos[u] = atomicAdd(&cursor[dst[u]], 1);

    // phase 3: stores
    #pragma unroll
    for (int u = 0; u < 2; ++u) {
        if (!ok[u]) continue;
        rec[2 * (size_t)pos[u]]     = make_uint4((uint)src[u], pack2(ca[u].x, ca[u].y), pack2(ca[u].z, ca[u].w), 0u);
        rec[2 * (size_t)pos[u] + 1] = make_uint4((uint)src[u], pack2(cb[u].x, cb[u].y), pack2(cb[u].z, cb[u].w), 0u);
    }
}

// ---------------- fused per-layer aggregate + MFMA GEMM ----------------
// block = 16 nodes (grid 3125, exact). Phase A: wave wid aggregates nodes
// m0+wid*4..+3 into LDS y-tile [16][264] bf16 (+8 ushort row pad: MFMA-phase
// ds_read_b128 row stride 528B -> 2-way bank aliasing = free; unpadded 512B
// would be 16-way). Phase B: wave wid owns output quadrant ct=wid; A-frags
// kb<8 from LDS, kb 8..9 from global hb rows; B-frags from L2-hot Bsw.
// out[n][c] = sum_{k<320} [y|hb][n][k] * W[k][c] + bias[c]
__global__ __launch_bounds__(256) void aggemm_k(const int* __restrict__ start,
                                                const int* __restrict__ counts,
                                                const uint4* __restrict__ recs,  // rec (+1 for layer 1)
                                                const ushort* __restrict__ hb,   // [N][64] bf16 input
                                                const ushort* __restrict__ Bsw,  // [2560][8] bf16 frag order
                                                const float* __restrict__ bias,  // [64]
                                                float* __restrict__ outf,        // fp32 out or null
                                                ushort* __restrict__ outh,       // next hb or null
                                                int relu) {
    __shared__ __align__(16) ushort ylds[16][264];   // 8.25 KB; 16B-aligned base for ds_read_b128
    const int tid = threadIdx.x;
    const int lane = tid & 63;
    const int wid = tid >> 6;
    const int m0 = blockIdx.x * 16;

    // ---- phase A: aggregate 4 nodes per wave ----
    for (int t = 0; t < 4; ++t) {
        int node = m0 + wid * 4 + t;
        int s = start[node];
        int cnt = counts[node];
        float y0 = 0.f, y1 = 0.f, y2 = 0.f, y3 = 0.f;
        int j = 0;
        for (; j + 7 < cnt; j += 8) {
            uint4 r[8];
            #pragma unroll
            for (int i = 0; i < 8; ++i) r[i] = recs[2 * (size_t)(s + j + i)];
            float hv[8];
            #pragma unroll
            for (int i = 0; i < 8; ++i) hv[i] = bf2f(hb[(size_t)r[i].x * 64 + lane]);
            #pragma unroll
            for (int i = 0; i < 8; ++i) {
                y0 = fmaf(bflo(r[i].y), hv[i], y0);
                y1 = fmaf(bfhi(r[i].y), hv[i], y1);
                y2 = fmaf(bflo(r[i].z), hv[i], y2);
                y3 = fmaf(bfhi(r[i].z), hv[i], y3);
            }
        }
        for (; j + 1 < cnt; j += 2) {
            uint4 ra = recs[2 * (size_t)(s + j)];
            uint4 rb = recs[2 * (size_t)(s + j + 1)];
            float ha = bf2f(hb[(size_t)ra.x * 64 + lane]);
            float hbv = bf2f(hb[(size_t)rb.x * 64 + lane]);
            y0 = fmaf(bflo(ra.y), ha, y0); y1 = fmaf(bfhi(ra.y), ha, y1);
            y2 = fmaf(bflo(ra.z), ha, y2); y3 = fmaf(bfhi(ra.z), ha, y3);
            y0 = fmaf(bflo(rb.y), hbv, y0); y1 = fmaf(bfhi(rb.y), hbv, y1);
            y2 = fmaf(bflo(rb.z), hbv, y2); y3 = fmaf(bfhi(rb.z), hbv, y3);
        }
        if (j < cnt) {
            uint4 r = recs[2 * (size_t)(s + j)];
            float hv = bf2f(hb[(size_t)r.x * 64 + lane]);
            y0 = fmaf(bflo(r.y), hv, y0); y1 = fmaf(bfhi(r.y), hv, y1);
            y2 = fmaf(bflo(r.z), hv, y2); y3 = fmaf(bfhi(r.z), hv, y3);
        }
        int nl = wid * 4 + t;
        ylds[nl][lane]       = f2bf(y0);
        ylds[nl][64 + lane]  = f2bf(y1);
        ylds[nl][128 + lane] = f2bf(y2);
        ylds[nl][192 + lane] = f2bf(y3);
    }
    __syncthreads();

    // ---- phase B: MFMA, wave wid -> ct = wid ----
    const int nlo = lane & 15;
    const int quad = lane >> 4;
    const int ct = wid;
    floatx4 acc = (floatx4){0.f, 0.f, 0.f, 0.f};

    const ushort* hrow = hb + (size_t)(m0 + nlo) * 64 + quad * 8;
    #pragma unroll
    for (int kb = 0; kb < 10; ++kb) {
        short8 a;
        if (kb < 8) a = *(const short8*)&ylds[nlo][quad * 8 + kb * 32];
        else        a = __builtin_bit_cast(short8, *(const uint4*)(hrow + (kb - 8) * 32));
        short8 b = __builtin_bit_cast(short8, ((const uint4*)Bsw)[(kb * 4 + ct) * 64 + lane]);
        acc = __builtin_amdgcn_mfma_f32_16x16x32_bf16(a, b, acc, 0, 0, 0);
    }

    // C/D layout: col = ct*16 + (lane&15), row = quad*4 + reg
    int col = ct * 16 + nlo;
    float bv = bias[col];
    #pragma unroll
    for (int r = 0; r < 4; ++r) {
        int row = m0 + quad * 4 + r;   // < 50000 always (3125*16 exact)
        float v = acc[r] + bv;
        if (relu) v = fmaxf(v, 0.f);
        if (outf) outf[(size_t)row * 64 + col] = v;
        if (outh) outh[(size_t)row * 64 + col] = f2bf(v);
    }
}

// ---------------- launch ----------------

extern "C" void kernel_launch(void* const* d_in, const int* in_sizes, int n_in,
                              void* d_out, int out_size, void* d_ws, size_t ws_size,
                              hipStream_t stream) {
    const float* x     = (const float*)d_in[0];
    const int*   ei    = (const int*)d_in[1];
    const float* ea    = (const float*)d_in[2];
    const float* basis = (const float*)d_in[3];  // [2,4,64,64]
    const float* att   = (const float*)d_in[4];  // [2,8,4]
    const float* root  = (const float*)d_in[5];  // [2,64,64]
    const float* bias  = (const float*)d_in[6];  // [2,64]
    float* out = (float*)d_out;

    char* p = (char*)d_ws;
    uint4*  rec    = (uint4*)p;   p += (size_t)N_EDGES * 32;          // 25.6 MB
    ushort* hb0    = (ushort*)p;  p += (size_t)N_PADROWS * 64 * 2;    //  6.4 MB (x bf16)
    ushort* hb1    = (ushort*)p;  p += (size_t)N_PADROWS * 64 * 2;    //  6.4 MB (h1 bf16)
    ushort* Bsw    = (ushort*)p;  p += (size_t)2 * 20480 * 2;         //  80 KB
    int*    counts = (int*)p;     p += (size_t)N_NODES * 4;
    int*    start  = (int*)p;     p += (size_t)N_NODES * 4;
    int*    cursor = (int*)p;     p += (size_t)N_NODES * 4;
    int*    bsums  = (int*)p;     p += 64 * 4;

    const int scan_blocks = (N_NODES + 1023) / 1024;  // 49

    init_k<<<INIT_BLOCKS, 256, 0, stream>>>(x, hb0, counts, basis, root, Bsw);
    hist_k<<<(N_EDGES + 255) / 256, 256, 0, stream>>>(ei, counts);
    scan1_k<<<scan_blocks, 1024, 0, stream>>>(counts, start, bsums);
    scan2_k<<<1, 64, 0, stream>>>(bsums, scan_blocks);
    scan3_k<<<(N_NODES + 255) / 256, 256, 0, stream>>>(start, cursor, bsums);
    scatter_k<<<(N_EDGES + 511) / 512, 256, 0, stream>>>(ei, ea, att, cursor, rec);

    dim3 f_grid(N_NODES / 16);   // 3125, exact

    // ---- layer 0: h = x (hb0) -> h1 bf16 (hb1) ----
    aggemm_k<<<f_grid, 256, 0, stream>>>(start, counts, rec, hb0, Bsw, bias, (float*)0, hb1, 1);

    // ---- layer 1: h = h1 (hb1) -> out fp32 ----
    aggemm_k<<<f_grid, 256, 0, stream>>>(start, counts, rec + 1, hb1, Bsw + 20480, bias + 64, out, (ushort*)0, 0);
}

// Round 6
// 279.383 us; speedup vs baseline: 1.5682x; 1.0128x over previous
//
#include <hip/hip_runtime.h>

#define N_NODES 50000
#define N_EDGES 800000
#define N_PADROWS 50048   // kept for buffer sizing

typedef unsigned int uint;
typedef unsigned short ushort;

typedef __attribute__((ext_vector_type(8))) short short8;
typedef __attribute__((ext_vector_type(4))) float floatx4;

__device__ __forceinline__ ushort f2bf(float f) {
    uint u = __builtin_bit_cast(uint, f);
    u += 0x7fffu + ((u >> 16) & 1u);      // round-to-nearest-even
    return (ushort)(u >> 16);
}
__device__ __forceinline__ float bf2f(ushort h) {
    uint u = ((uint)h) << 16;
    return __builtin_bit_cast(float, u);
}
__device__ __forceinline__ float bflo(uint w) { return __builtin_bit_cast(float, w << 16); }
__device__ __forceinline__ float bfhi(uint w) { return __builtin_bit_cast(float, w & 0xffff0000u); }
__device__ __forceinline__ uint pack2(float a, float b) {
    return (uint)f2bf(a) | ((uint)f2bf(b) << 16);
}

// ---------------- fused init: conv (x->bf16) + zero counts + weight prep ----------------
// block ranges: [0,1563) conv, [1563,1759) zero, [1759,1919) prep
#define CONV_BLOCKS 1563
#define ZERO_BLOCKS 196
#define PREP_BLOCKS 160
#define INIT_BLOCKS (CONV_BLOCKS + ZERO_BLOCKS + PREP_BLOCKS)

__global__ __launch_bounds__(256) void init_k(const float* __restrict__ x,
                                              ushort* __restrict__ hb,
                                              int* __restrict__ counts,
                                              const float* __restrict__ basis,
                                              const float* __restrict__ root,
                                              ushort* __restrict__ Bsw) {
    int b = blockIdx.x;
    if (b < CONV_BLOCKS) {
        // x fp32 -> dense bf16 [N][64], 8 floats per thread
        int i = b * 256 + threadIdx.x;
        if (i >= N_NODES * 8) return;
        const float4* p = (const float4*)(x + (size_t)i * 8);
        float4 a = p[0], c = p[1];
        uint4 o;
        o.x = pack2(a.x, a.y); o.y = pack2(a.z, a.w);
        o.z = pack2(c.x, c.y); o.w = pack2(c.z, c.w);
        *(uint4*)(hb + (size_t)i * 8) = o;
    } else if (b < CONV_BLOCKS + ZERO_BLOCKS) {
        int i = (b - CONV_BLOCKS) * 256 + threadIdx.x;
        if (i < N_NODES) counts[i] = 0;
    } else {
        // Bsw[l][kb][ct][q][n][j] = W_l[kb*32+q*8+j][ct*16+n], W_l = [basis_l ; root_l]
        int idx = (b - (CONV_BLOCKS + ZERO_BLOCKS)) * 256 + threadIdx.x;
        if (idx >= 2 * 20480) return;
        int l = idx / 20480;
        int r = idx % 20480;
        int kb = r >> 11, ct = (r >> 9) & 3, q = (r >> 7) & 3, n = (r >> 3) & 15, j = r & 7;
        int k = kb * 32 + q * 8 + j;
        int c = ct * 16 + n;
        float v = (k < 256) ? basis[(size_t)l * 16384 + k * 64 + c]
                            : root[(size_t)l * 4096 + (k - 256) * 64 + c];
        Bsw[idx] = f2bf(v);
    }
}

// ---------------- CSR build ----------------

__global__ __launch_bounds__(256) void hist_k(const int* __restrict__ ei, int* __restrict__ counts) {
    int e = blockIdx.x * 256 + threadIdx.x;
    if (e < N_EDGES) atomicAdd(&counts[ei[N_EDGES + e]], 1);
}

__global__ __launch_bounds__(1024) void scan1_k(const int* __restrict__ counts,
                                                int* __restrict__ start,
                                                int* __restrict__ bsums) {
    __shared__ int s[1024];
    int i = blockIdx.x * 1024 + threadIdx.x;
    int x = (i < N_NODES) ? counts[i] : 0;
    s[threadIdx.x] = x;
    __syncthreads();
    for (int off = 1; off < 1024; off <<= 1) {
        int v = (threadIdx.x >= off) ? s[threadIdx.x - off] : 0;
        __syncthreads();
        s[threadIdx.x] += v;
        __syncthreads();
    }
    if (i < N_NODES) start[i] = s[threadIdx.x] - x;
    if (threadIdx.x == 1023) bsums[blockIdx.x] = s[1023];
}

// wave-parallel exclusive scan over block sums (nblocks <= 64, one wave)
__global__ void scan2_k(int* __restrict__ bsums, int nblocks) {
    int lane = threadIdx.x;           // launched with 64 threads = one wave
    int v = (lane < nblocks) ? bsums[lane] : 0;
    int x = v;
    #pragma unroll
    for (int off = 1; off < 64; off <<= 1) {
        int t = __shfl_up(x, off, 64);
        if (lane >= off) x += t;
    }
    if (lane < nblocks) bsums[lane] = x - v;   // exclusive
}

__global__ __launch_bounds__(256) void scan3_k(int* __restrict__ start,
                                               int* __restrict__ cursor,
                                               const int* __restrict__ bsums) {
    int i = blockIdx.x * 256 + threadIdx.x;
    if (i < N_NODES) {
        int v = start[i] + bsums[i >> 10];
        start[i] = v;
        cursor[i] = v;
    }
}

// single-pass scatter — EXACT round-1 proven form (1 edge/thread, max TLP).
// (round-5 lesson: 2-edge ILP unroll halved wave count and regressed 47->62 µs;
//  scatter is TLP-saturated DRAM random-line-bound, not in-flight-latency-bound)
// per edge: both layers' c = ea @ att; ONE 64B-line record pair at the CSR slot.
// rec[2*pos] = {src, c0lo, c0hi, 0}, rec[2*pos+1] = {src, c1lo, c1hi, 0}
__global__ __launch_bounds__(256) void scatter_k(const int* __restrict__ ei,
                                                 const float* __restrict__ ea,
                                                 const float* __restrict__ att,   // [2,8,4]
                                                 int* __restrict__ cursor,
                                                 uint4* __restrict__ rec) {
    int e = blockIdx.x * 256 + threadIdx.x;
    if (e >= N_EDGES) return;
    int src = ei[e];
    int dst = ei[N_EDGES + e];

    const float4* eav = (const float4*)(ea + (size_t)e * 8);
    float4 a0 = eav[0], a1 = eav[1];
    float ev[8] = {a0.x, a0.y, a0.z, a0.w, a1.x, a1.y, a1.z, a1.w};

    float4 c0 = make_float4(0.f, 0.f, 0.f, 0.f);
    float4 c1 = make_float4(0.f, 0.f, 0.f, 0.f);
    const float4* att0 = (const float4*)att;
    const float4* att1 = (const float4*)(att + 32);
    #pragma unroll
    for (int r = 0; r < 8; ++r) {
        float4 w0 = att0[r];
        float4 w1 = att1[r];
        c0.x = fmaf(ev[r], w0.x, c0.x); c0.y = fmaf(ev[r], w0.y, c0.y);
        c0.z = fmaf(ev[r], w0.z, c0.z); c0.w = fmaf(ev[r], w0.w, c0.w);
        c1.x = fmaf(ev[r], w1.x, c1.x); c1.y = fmaf(ev[r], w1.y, c1.y);
        c1.z = fmaf(ev[r], w1.z, c1.z); c1.w = fmaf(ev[r], w1.w, c1.w);
    }
    int pos = atomicAdd(&cursor[dst], 1);
    rec[2 * (size_t)pos]     = make_uint4((uint)src, pack2(c0.x, c0.y), pack2(c0.z, c0.w), 0u);
    rec[2 * (size_t)pos + 1] = make_uint4((uint)src, pack2(c1.x, c1.y), pack2(c1.z, c1.w), 0u);
}

// ---------------- fused per-layer aggregate + MFMA GEMM ----------------
// block = 16 nodes (grid 3125, exact). Phase A: wave wid aggregates nodes
// m0+wid*4..+3 into LDS y-tile [16][264] bf16 (+8 ushort row pad: MFMA-phase
// ds_read_b128 row stride 528B -> 2-way bank aliasing = free; unpadded 512B
// would be 16-way). Phase B: wave wid owns output quadrant ct=wid; A-frags
// kb<8 from LDS, kb 8..9 from global hb rows; B-frags from L2-hot Bsw.
// out[n][c] = sum_{k<320} [y|hb][n][k] * W[k][c] + bias[c]
__global__ __launch_bounds__(256) void aggemm_k(const int* __restrict__ start,
                                                const int* __restrict__ counts,
                                                const uint4* __restrict__ recs,  // rec (+1 for layer 1)
                                                const ushort* __restrict__ hb,   // [N][64] bf16 input
                                                const ushort* __restrict__ Bsw,  // [2560][8] bf16 frag order
                                                const float* __restrict__ bias,  // [64]
                                                float* __restrict__ outf,        // fp32 out or null
                                                ushort* __restrict__ outh,       // next hb or null
                                                int relu) {
    __shared__ __align__(16) ushort ylds[16][264];   // 8.25 KB; 16B-aligned base for ds_read_b128
    const int tid = threadIdx.x;
    const int lane = tid & 63;
    const int wid = tid >> 6;
    const int m0 = blockIdx.x * 16;

    // ---- phase A: aggregate 4 nodes per wave ----
    for (int t = 0; t < 4; ++t) {
        int node = m0 + wid * 4 + t;
        int s = start[node];
        int cnt = counts[node];
        float y0 = 0.f, y1 = 0.f, y2 = 0.f, y3 = 0.f;
        int j = 0;
        for (; j + 7 < cnt; j += 8) {
            uint4 r[8];
            #pragma unroll
            for (int i = 0; i < 8; ++i) r[i] = recs[2 * (size_t)(s + j + i)];
            float hv[8];
            #pragma unroll
            for (int i = 0; i < 8; ++i) hv[i] = bf2f(hb[(size_t)r[i].x * 64 + lane]);
            #pragma unroll
            for (int i = 0; i < 8; ++i) {
                y0 = fmaf(bflo(r[i].y), hv[i], y0);
                y1 = fmaf(bfhi(r[i].y), hv[i], y1);
                y2 = fmaf(bflo(r[i].z), hv[i], y2);
                y3 = fmaf(bfhi(r[i].z), hv[i], y3);
            }
        }
        for (; j + 1 < cnt; j += 2) {
            uint4 ra = recs[2 * (size_t)(s + j)];
            uint4 rb = recs[2 * (size_t)(s + j + 1)];
            float ha = bf2f(hb[(size_t)ra.x * 64 + lane]);
            float hbv = bf2f(hb[(size_t)rb.x * 64 + lane]);
            y0 = fmaf(bflo(ra.y), ha, y0); y1 = fmaf(bfhi(ra.y), ha, y1);
            y2 = fmaf(bflo(ra.z), ha, y2); y3 = fmaf(bfhi(ra.z), ha, y3);
            y0 = fmaf(bflo(rb.y), hbv, y0); y1 = fmaf(bfhi(rb.y), hbv, y1);
            y2 = fmaf(bflo(rb.z), hbv, y2); y3 = fmaf(bfhi(rb.z), hbv, y3);
        }
        if (j < cnt) {
            uint4 r = recs[2 * (size_t)(s + j)];
            float hv = bf2f(hb[(size_t)r.x * 64 + lane]);
            y0 = fmaf(bflo(r.y), hv, y0); y1 = fmaf(bfhi(r.y), hv, y1);
            y2 = fmaf(bflo(r.z), hv, y2); y3 = fmaf(bfhi(r.z), hv, y3);
        }
        int nl = wid * 4 + t;
        ylds[nl][lane]       = f2bf(y0);
        ylds[nl][64 + lane]  = f2bf(y1);
        ylds[nl][128 + lane] = f2bf(y2);
        ylds[nl][192 + lane] = f2bf(y3);
    }
    __syncthreads();

    // ---- phase B: MFMA, wave wid -> ct = wid ----
    const int nlo = lane & 15;
    const int quad = lane >> 4;
    const int ct = wid;
    floatx4 acc = (floatx4){0.f, 0.f, 0.f, 0.f};

    const ushort* hrow = hb + (size_t)(m0 + nlo) * 64 + quad * 8;
    #pragma unroll
    for (int kb = 0; kb < 10; ++kb) {
        short8 a;
        if (kb < 8) a = *(const short8*)&ylds[nlo][quad * 8 + kb * 32];
        else        a = __builtin_bit_cast(short8, *(const uint4*)(hrow + (kb - 8) * 32));
        short8 b = __builtin_bit_cast(short8, ((const uint4*)Bsw)[(kb * 4 + ct) * 64 + lane]);
        acc = __builtin_amdgcn_mfma_f32_16x16x32_bf16(a, b, acc, 0, 0, 0);
    }

    // C/D layout: col = ct*16 + (lane&15), row = quad*4 + reg
    int col = ct * 16 + nlo;
    float bv = bias[col];
    #pragma unroll
    for (int r = 0; r < 4; ++r) {
        int row = m0 + quad * 4 + r;   // < 50000 always (3125*16 exact)
        float v = acc[r] + bv;
        if (relu) v = fmaxf(v, 0.f);
        if (outf) outf[(size_t)row * 64 + col] = v;
        if (outh) outh[(size_t)row * 64 + col] = f2bf(v);
    }
}

// ---------------- launch ----------------

extern "C" void kernel_launch(void* const* d_in, const int* in_sizes, int n_in,
                              void* d_out, int out_size, void* d_ws, size_t ws_size,
                              hipStream_t stream) {
    const float* x     = (const float*)d_in[0];
    const int*   ei    = (const int*)d_in[1];
    const float* ea    = (const float*)d_in[2];
    const float* basis = (const float*)d_in[3];  // [2,4,64,64]
    const float* att   = (const float*)d_in[4];  // [2,8,4]
    const float* root  = (const float*)d_in[5];  // [2,64,64]
    const float* bias  = (const float*)d_in[6];  // [2,64]
    float* out = (float*)d_out;

    char* p = (char*)d_ws;
    uint4*  rec    = (uint4*)p;   p += (size_t)N_EDGES * 32;          // 25.6 MB
    ushort* hb0    = (ushort*)p;  p += (size_t)N_PADROWS * 64 * 2;    //  6.4 MB (x bf16)
    ushort* hb1    = (ushort*)p;  p += (size_t)N_PADROWS * 64 * 2;    //  6.4 MB (h1 bf16)
    ushort* Bsw    = (ushort*)p;  p += (size_t)2 * 20480 * 2;         //  80 KB
    int*    counts = (int*)p;     p += (size_t)N_NODES * 4;
    int*    start  = (int*)p;     p += (size_t)N_NODES * 4;
    int*    cursor = (int*)p;     p += (size_t)N_NODES * 4;
    int*    bsums  = (int*)p;     p += 64 * 4;

    const int scan_blocks = (N_NODES + 1023) / 1024;  // 49

    init_k<<<INIT_BLOCKS, 256, 0, stream>>>(x, hb0, counts, basis, root, Bsw);
    hist_k<<<(N_EDGES + 255) / 256, 256, 0, stream>>>(ei, counts);
    scan1_k<<<scan_blocks, 1024, 0, stream>>>(counts, start, bsums);
    scan2_k<<<1, 64, 0, stream>>>(bsums, scan_blocks);
    scan3_k<<<(N_NODES + 255) / 256, 256, 0, stream>>>(start, cursor, bsums);
    scatter_k<<<(N_EDGES + 255) / 256, 256, 0, stream>>>(ei, ea, att, cursor, rec);

    dim3 f_grid(N_NODES / 16);   // 3125, exact

    // ---- layer 0: h = x (hb0) -> h1 bf16 (hb1) ----
    aggemm_k<<<f_grid, 256, 0, stream>>>(start, counts, rec, hb0, Bsw, bias, (float*)0, hb1, 1);

    // ---- layer 1: h = h1 (hb1) -> out fp32 ----
    aggemm_k<<<f_grid, 256, 0, stream>>>(start, counts, rec + 1, hb1, Bsw + 20480, bias + 64, out, (ushort*)0, 0);
}

// Round 7
// 251.004 us; speedup vs baseline: 1.7455x; 1.1131x over previous
//
#include <hip/hip_runtime.h>

#define N_NODES 50000
#define N_EDGES 800000
#define N_PADROWS 50048   // kept for buffer sizing

typedef unsigned int uint;
typedef unsigned short ushort;

typedef __attribute__((ext_vector_type(8))) short short8;
typedef __attribute__((ext_vector_type(4))) float floatx4;

__device__ __forceinline__ ushort f2bf(float f) {
    uint u = __builtin_bit_cast(uint, f);
    u += 0x7fffu + ((u >> 16) & 1u);      // round-to-nearest-even
    return (ushort)(u >> 16);
}
__device__ __forceinline__ float bf2f(ushort h) {
    uint u = ((uint)h) << 16;
    return __builtin_bit_cast(float, u);
}
__device__ __forceinline__ float bflo(uint w) { return __builtin_bit_cast(float, w << 16); }
__device__ __forceinline__ float bfhi(uint w) { return __builtin_bit_cast(float, w & 0xffff0000u); }
__device__ __forceinline__ uint pack2(float a, float b) {
    return (uint)f2bf(a) | ((uint)f2bf(b) << 16);
}

// ---------------- fused init: hist + conv (x->bf16) + weight prep ----------------
// counts zeroed by hipMemsetAsync before this kernel (stream-ordered).
// block ranges: [0,3125) hist, [3125,4688) conv, [4688,4848) prep
#define HIST_BLOCKS 3125
#define CONV_BLOCKS 1563
#define PREP_BLOCKS 160
#define INIT_BLOCKS (HIST_BLOCKS + CONV_BLOCKS + PREP_BLOCKS)

__global__ __launch_bounds__(256) void init_k(const int* __restrict__ ei,
                                              const float* __restrict__ x,
                                              ushort* __restrict__ hb,
                                              int* __restrict__ counts,
                                              const float* __restrict__ basis,
                                              const float* __restrict__ root,
                                              ushort* __restrict__ Bsw) {
    int b = blockIdx.x;
    if (b < HIST_BLOCKS) {
        int e = b * 256 + threadIdx.x;
        if (e < N_EDGES) atomicAdd(&counts[ei[N_EDGES + e]], 1);
    } else if (b < HIST_BLOCKS + CONV_BLOCKS) {
        // x fp32 -> dense bf16 [N][64], 8 floats per thread
        int i = (b - HIST_BLOCKS) * 256 + threadIdx.x;
        if (i >= N_NODES * 8) return;
        const float4* p = (const float4*)(x + (size_t)i * 8);
        float4 a = p[0], c = p[1];
        uint4 o;
        o.x = pack2(a.x, a.y); o.y = pack2(a.z, a.w);
        o.z = pack2(c.x, c.y); o.w = pack2(c.z, c.w);
        *(uint4*)(hb + (size_t)i * 8) = o;
    } else {
        // Bsw[l][kb][ct][q][n][j] = W_l[kb*32+q*8+j][ct*16+n], W_l = [basis_l ; root_l]
        int idx = (b - (HIST_BLOCKS + CONV_BLOCKS)) * 256 + threadIdx.x;
        if (idx >= 2 * 20480) return;
        int l = idx / 20480;
        int r = idx % 20480;
        int kb = r >> 11, ct = (r >> 9) & 3, q = (r >> 7) & 3, n = (r >> 3) & 15, j = r & 7;
        int k = kb * 32 + q * 8 + j;
        int c = ct * 16 + n;
        float v = (k < 256) ? basis[(size_t)l * 16384 + k * 64 + c]
                            : root[(size_t)l * 4096 + (k - 256) * 64 + c];
        Bsw[idx] = f2bf(v);
    }
}

// ---------------- CSR scan ----------------

__global__ __launch_bounds__(1024) void scan1_k(const int* __restrict__ counts,
                                                int* __restrict__ start,
                                                int* __restrict__ bsums) {
    __shared__ int s[1024];
    int i = blockIdx.x * 1024 + threadIdx.x;
    int x = (i < N_NODES) ? counts[i] : 0;
    s[threadIdx.x] = x;
    __syncthreads();
    for (int off = 1; off < 1024; off <<= 1) {
        int v = (threadIdx.x >= off) ? s[threadIdx.x - off] : 0;
        __syncthreads();
        s[threadIdx.x] += v;
        __syncthreads();
    }
    if (i < N_NODES) start[i] = s[threadIdx.x] - x;
    if (threadIdx.x == 1023) bsums[blockIdx.x] = s[1023];
}

// wave-parallel exclusive scan over block sums (nblocks <= 64, one wave)
__global__ void scan2_k(int* __restrict__ bsums, int nblocks) {
    int lane = threadIdx.x;           // launched with 64 threads = one wave
    int v = (lane < nblocks) ? bsums[lane] : 0;
    int x = v;
    #pragma unroll
    for (int off = 1; off < 64; off <<= 1) {
        int t = __shfl_up(x, off, 64);
        if (lane >= off) x += t;
    }
    if (lane < nblocks) bsums[lane] = x - v;   // exclusive
}

__global__ __launch_bounds__(256) void scan3_k(int* __restrict__ start,
                                               int* __restrict__ cursor,
                                               const int* __restrict__ bsums) {
    int i = blockIdx.x * 256 + threadIdx.x;
    if (i < N_NODES) {
        int v = start[i] + bsums[i >> 10];
        start[i] = v;
        cursor[i] = v;
    }
}

// single-pass scatter — round-1 proven form (1 edge/thread, max TLP).
// (round-5 lesson: 2-edge ILP unroll halved wave count and regressed 47->62 µs;
//  scatter is TLP-saturated DRAM random-line-bound, not in-flight-latency-bound)
// per edge: both layers' c = ea @ att; ONE 64B-line record pair at the CSR slot.
// rec[2*pos] = {src, c0lo, c0hi, 0}, rec[2*pos+1] = {src, c1lo, c1hi, 0}
__global__ __launch_bounds__(256) void scatter_k(const int* __restrict__ ei,
                                                 const float* __restrict__ ea,
                                                 const float* __restrict__ att,   // [2,8,4]
                                                 int* __restrict__ cursor,
                                                 uint4* __restrict__ rec) {
    int e = blockIdx.x * 256 + threadIdx.x;
    if (e >= N_EDGES) return;
    int src = ei[e];
    int dst = ei[N_EDGES + e];

    const float4* eav = (const float4*)(ea + (size_t)e * 8);
    float4 a0 = eav[0], a1 = eav[1];
    float ev[8] = {a0.x, a0.y, a0.z, a0.w, a1.x, a1.y, a1.z, a1.w};

    float4 c0 = make_float4(0.f, 0.f, 0.f, 0.f);
    float4 c1 = make_float4(0.f, 0.f, 0.f, 0.f);
    const float4* att0 = (const float4*)att;
    const float4* att1 = (const float4*)(att + 32);
    #pragma unroll
    for (int r = 0; r < 8; ++r) {
        float4 w0 = att0[r];
        float4 w1 = att1[r];
        c0.x = fmaf(ev[r], w0.x, c0.x); c0.y = fmaf(ev[r], w0.y, c0.y);
        c0.z = fmaf(ev[r], w0.z, c0.z); c0.w = fmaf(ev[r], w0.w, c0.w);
        c1.x = fmaf(ev[r], w1.x, c1.x); c1.y = fmaf(ev[r], w1.y, c1.y);
        c1.z = fmaf(ev[r], w1.z, c1.z); c1.w = fmaf(ev[r], w1.w, c1.w);
    }
    int pos = atomicAdd(&cursor[dst], 1);
    rec[2 * (size_t)pos]     = make_uint4((uint)src, pack2(c0.x, c0.y), pack2(c0.z, c0.w), 0u);
    rec[2 * (size_t)pos + 1] = make_uint4((uint)src, pack2(c1.x, c1.y), pack2(c1.z, c1.w), 0u);
}

// ---------------- fused per-layer aggregate + MFMA GEMM ----------------
// block = 16 nodes (grid 3125, exact). Phase A: wave wid aggregates nodes
// m0+wid*4..+3 into LDS y-tile [16][264] bf16. KEY: s/cnt/r.x forced wave-
// uniform via readfirstlane so the compiler can emit scalar record loads
// (SMEM pipe), SALU coefficient unpacks, and saddr-form hb gathers — round-6
// counters showed ~40% of aggemm time was per-lane VALU on uniform values.
// Phase B: wave wid owns output quadrant ct=wid; A-frags kb<8 from LDS,
// kb 8..9 from global hb rows; B-frags from L2-hot Bsw.
// out[n][c] = sum_{k<320} [y|hb][n][k] * W[k][c] + bias[c]
__global__ __launch_bounds__(256) void aggemm_k(const int* __restrict__ start,
                                                const int* __restrict__ counts,
                                                const uint4* __restrict__ recs,  // rec (+1 for layer 1)
                                                const ushort* __restrict__ hb,   // [N][64] bf16 input
                                                const ushort* __restrict__ Bsw,  // [2560][8] bf16 frag order
                                                const float* __restrict__ bias,  // [64]
                                                float* __restrict__ outf,        // fp32 out or null
                                                ushort* __restrict__ outh,       // next hb or null
                                                int relu) {
    __shared__ __align__(16) ushort ylds[16][264];   // 8.25 KB; 16B-aligned base for ds_read_b128
    const int tid = threadIdx.x;
    const int lane = tid & 63;
    const int wid = tid >> 6;
    const int m0 = blockIdx.x * 16;

    // ---- phase A: aggregate 4 nodes per wave ----
    for (int t = 0; t < 4; ++t) {
        int node = m0 + wid * 4 + t;
        int s   = __builtin_amdgcn_readfirstlane(start[node]);
        int cnt = __builtin_amdgcn_readfirstlane(counts[node]);
        float y0 = 0.f, y1 = 0.f, y2 = 0.f, y3 = 0.f;
        int j = 0;
        for (; j + 7 < cnt; j += 8) {
            uint4 r[8];
            #pragma unroll
            for (int i = 0; i < 8; ++i) r[i] = recs[2 * (size_t)(s + j + i)];
            float hv[8];
            #pragma unroll
            for (int i = 0; i < 8; ++i) {
                int srow = __builtin_amdgcn_readfirstlane((int)r[i].x);
                hv[i] = bf2f(hb[(size_t)srow * 64 + lane]);
            }
            #pragma unroll
            for (int i = 0; i < 8; ++i) {
                y0 = fmaf(bflo(r[i].y), hv[i], y0);
                y1 = fmaf(bfhi(r[i].y), hv[i], y1);
                y2 = fmaf(bflo(r[i].z), hv[i], y2);
                y3 = fmaf(bfhi(r[i].z), hv[i], y3);
            }
        }
        for (; j + 1 < cnt; j += 2) {
            uint4 ra = recs[2 * (size_t)(s + j)];
            uint4 rb = recs[2 * (size_t)(s + j + 1)];
            int sa = __builtin_amdgcn_readfirstlane((int)ra.x);
            int sb = __builtin_amdgcn_readfirstlane((int)rb.x);
            float ha = bf2f(hb[(size_t)sa * 64 + lane]);
            float hbv = bf2f(hb[(size_t)sb * 64 + lane]);
            y0 = fmaf(bflo(ra.y), ha, y0); y1 = fmaf(bfhi(ra.y), ha, y1);
            y2 = fmaf(bflo(ra.z), ha, y2); y3 = fmaf(bfhi(ra.z), ha, y3);
            y0 = fmaf(bflo(rb.y), hbv, y0); y1 = fmaf(bfhi(rb.y), hbv, y1);
            y2 = fmaf(bflo(rb.z), hbv, y2); y3 = fmaf(bfhi(rb.z), hbv, y3);
        }
        if (j < cnt) {
            uint4 r = recs[2 * (size_t)(s + j)];
            int sr = __builtin_amdgcn_readfirstlane((int)r.x);
            float hv = bf2f(hb[(size_t)sr * 64 + lane]);
            y0 = fmaf(bflo(r.y), hv, y0); y1 = fmaf(bfhi(r.y), hv, y1);
            y2 = fmaf(bflo(r.z), hv, y2); y3 = fmaf(bfhi(r.z), hv, y3);
        }
        int nl = wid * 4 + t;
        ylds[nl][lane]       = f2bf(y0);
        ylds[nl][64 + lane]  = f2bf(y1);
        ylds[nl][128 + lane] = f2bf(y2);
        ylds[nl][192 + lane] = f2bf(y3);
    }
    __syncthreads();

    // ---- phase B: MFMA, wave wid -> ct = wid ----
    const int nlo = lane & 15;
    const int quad = lane >> 4;
    const int ct = wid;
    floatx4 acc = (floatx4){0.f, 0.f, 0.f, 0.f};

    const ushort* hrow = hb + (size_t)(m0 + nlo) * 64 + quad * 8;
    #pragma unroll
    for (int kb = 0; kb < 10; ++kb) {
        short8 a;
        if (kb < 8) a = *(const short8*)&ylds[nlo][quad * 8 + kb * 32];
        else        a = __builtin_bit_cast(short8, *(const uint4*)(hrow + (kb - 8) * 32));
        short8 b = __builtin_bit_cast(short8, ((const uint4*)Bsw)[(kb * 4 + ct) * 64 + lane]);
        acc = __builtin_amdgcn_mfma_f32_16x16x32_bf16(a, b, acc, 0, 0, 0);
    }

    // C/D layout: col = ct*16 + (lane&15), row = quad*4 + reg
    int col = ct * 16 + nlo;
    float bv = bias[col];
    #pragma unroll
    for (int r = 0; r < 4; ++r) {
        int row = m0 + quad * 4 + r;   // < 50000 always (3125*16 exact)
        float v = acc[r] + bv;
        if (relu) v = fmaxf(v, 0.f);
        if (outf) outf[(size_t)row * 64 + col] = v;
        if (outh) outh[(size_t)row * 64 + col] = f2bf(v);
    }
}

// ---------------- launch ----------------

extern "C" void kernel_launch(void* const* d_in, const int* in_sizes, int n_in,
                              void* d_out, int out_size, void* d_ws, size_t ws_size,
                              hipStream_t stream) {
    const float* x     = (const float*)d_in[0];
    const int*   ei    = (const int*)d_in[1];
    const float* ea    = (const float*)d_in[2];
    const float* basis = (const float*)d_in[3];  // [2,4,64,64]
    const float* att   = (const float*)d_in[4];  // [2,8,4]
    const float* root  = (const float*)d_in[5];  // [2,64,64]
    const float* bias  = (const float*)d_in[6];  // [2,64]
    float* out = (float*)d_out;

    char* p = (char*)d_ws;
    uint4*  rec    = (uint4*)p;   p += (size_t)N_EDGES * 32;          // 25.6 MB
    ushort* hb0    = (ushort*)p;  p += (size_t)N_PADROWS * 64 * 2;    //  6.4 MB (x bf16)
    ushort* hb1    = (ushort*)p;  p += (size_t)N_PADROWS * 64 * 2;    //  6.4 MB (h1 bf16)
    ushort* Bsw    = (ushort*)p;  p += (size_t)2 * 20480 * 2;         //  80 KB
    int*    counts = (int*)p;     p += (size_t)N_NODES * 4;
    int*    start  = (int*)p;     p += (size_t)N_NODES * 4;
    int*    cursor = (int*)p;     p += (size_t)N_NODES * 4;
    int*    bsums  = (int*)p;     p += 64 * 4;

    const int scan_blocks = (N_NODES + 1023) / 1024;  // 49

    hipMemsetAsync(counts, 0, (size_t)N_NODES * 4, stream);
    init_k<<<INIT_BLOCKS, 256, 0, stream>>>(ei, x, hb0, counts, basis, root, Bsw);
    scan1_k<<<scan_blocks, 1024, 0, stream>>>(counts, start, bsums);
    scan2_k<<<1, 64, 0, stream>>>(bsums, scan_blocks);
    scan3_k<<<(N_NODES + 255) / 256, 256, 0, stream>>>(start, cursor, bsums);
    scatter_k<<<(N_EDGES + 255) / 256, 256, 0, stream>>>(ei, ea, att, cursor, rec);

    dim3 f_grid(N_NODES / 16);   // 3125, exact

    // ---- layer 0: h = x (hb0) -> h1 bf16 (hb1) ----
    aggemm_k<<<f_grid, 256, 0, stream>>>(start, counts, rec, hb0, Bsw, bias, (float*)0, hb1, 1);

    // ---- layer 1: h = h1 (hb1) -> out fp32 ----
    aggemm_k<<<f_grid, 256, 0, stream>>>(start, counts, rec + 1, hb1, Bsw + 20480, bias + 64, out, (ushort*)0, 0);
}